// Round 12
// baseline (17455.034 us; speedup 1.0000x reference)
//
#include <hip/hip_runtime.h>

// Aggregator forward: 2-layer LSTM + LN + chunk pivots + expected multi-head attention.
// B=8,T=1024,F=H=FF=512,K=32,CS=32,NH=8,HD=64. Outputs f32: [8,32,512] ++ [8,32,1024].
// Precision: all matmul operands as (hi,lo) bf16 pairs, bf16x3 MFMA (Ah*Bh+Al*Bh+Ah*Bl).
// LSTM: fused 2-layer persistent kernel, 64 blocks (32/layer). Whh-hi in LDS; Whh-lo,
// Wih2 from global (L2-cached). h wire [t][blk][b8][u16] u32(hi|lo<<16): producer
// bounces through double-buffered LDS outb, wave0 writes 512B contiguous agent stores
// + vmcnt + flag; consumers read MFMA A-fragments DIRECT from global (round-8-proven
// freshness), no LDS staging. 2 barriers/step. xg prefetch pipeline depth 4.

typedef unsigned short u16;
typedef __attribute__((ext_vector_type(8))) short bf16x8;
typedef __attribute__((ext_vector_type(4))) float f32x4;
typedef __attribute__((ext_vector_type(4))) unsigned int u32x4;

#define T_    1024

__device__ __forceinline__ float bf2f(u16 h) {
    union { unsigned int u; float f; } v; v.u = ((unsigned int)h) << 16; return v.f;
}
__device__ __forceinline__ u16 f2bf(float x) {
    union { float f; unsigned int u; } v; v.f = x;
    unsigned int r = (v.u + 0x7FFFu + ((v.u >> 16) & 1u)) >> 16;
    return (u16)r;
}
__device__ __forceinline__ float sigm(float x) { return 1.f / (1.f + __expf(-x)); }
__device__ __forceinline__ float tanhf_(float x) {
    float e = __expf(-2.f * fabsf(x));
    float t = (1.f - e) / (1.f + e);
    return x < 0.f ? -t : t;
}

// ---------------- split f32 -> (hi,lo) bf16 planes ----------------
__global__ __launch_bounds__(256) void k_split(const float* __restrict__ in,
                                               u16* __restrict__ hi, u16* __restrict__ lo, long n) {
    long i = ((long)blockIdx.x * 256 + threadIdx.x) * 4;
    if (i >= n) return;
    union { u16 h[4]; unsigned long long q; } ph, pl;
#pragma unroll
    for (int j = 0; j < 4; ++j) {
        float v = in[i + j];
        u16 h = f2bf(v);
        ph.h[j] = h;
        pl.h[j] = f2bf(v - bf2f(h));
    }
    *reinterpret_cast<unsigned long long*>(hi + i) = ph.q;
    *reinterpret_cast<unsigned long long*>(lo + i) = pl.q;
}

__global__ __launch_bounds__(256) void k_addvec(const float* __restrict__ a, const float* __restrict__ b,
                                                float* __restrict__ o, int n) {
    int i = blockIdx.x * 256 + threadIdx.x;
    if (i < n) o[i] = a[i] + b[i];
}

// ---------------- bf16x3 MFMA GEMM: C[M,N] = A[M,K] @ B[N,K]^T (+bias) ----------------
__global__ __launch_bounds__(256)
void k_gemm(const u16* __restrict__ Ah, const u16* __restrict__ Al,
            const u16* __restrict__ Bh, const u16* __restrict__ Bl,
            const float* __restrict__ bias,
            float* __restrict__ Cf, u16* __restrict__ Ch, u16* __restrict__ Cl,
            unsigned int* __restrict__ Cp, int xgfmt,
            int M, int N, int K, long sA, long sB, long sC)
{
    const int lane = threadIdx.x & 63;
    const int wave = threadIdx.x >> 6;
    const int wr = wave >> 1, wc = wave & 1;
    const long bz = blockIdx.z;
    const u16* Ahb = Ah + bz * sA;
    const u16* Alb = Al + bz * sA;
    const u16* Bhb = Bh + bz * sB;
    const u16* Blb = Bl + bz * sB;
    const int rowBase = blockIdx.y * 128 + wr * 64;
    const int colBase = blockIdx.x * 128 + wc * 64;
    const int lr = lane & 15;
    const int lk = (lane >> 4) * 8;

    f32x4 acc[4][4];
#pragma unroll
    for (int j = 0; j < 4; ++j) {
        float bv = bias ? bias[colBase + j * 16 + lr] : 0.f;
#pragma unroll
        for (int i = 0; i < 4; ++i) acc[i][j] = (f32x4){bv, bv, bv, bv};
    }
    for (int k0 = 0; k0 < K; k0 += 32) {
        bf16x8 ah[4], al[4], bh[4], bl[4];
#pragma unroll
        for (int i = 0; i < 4; ++i) {
            long off = (long)(rowBase + i * 16 + lr) * K + k0 + lk;
            ah[i] = *reinterpret_cast<const bf16x8*>(Ahb + off);
            al[i] = *reinterpret_cast<const bf16x8*>(Alb + off);
        }
#pragma unroll
        for (int j = 0; j < 4; ++j) {
            long off = (long)(colBase + j * 16 + lr) * K + k0 + lk;
            bh[j] = *reinterpret_cast<const bf16x8*>(Bhb + off);
            bl[j] = *reinterpret_cast<const bf16x8*>(Blb + off);
        }
#pragma unroll
        for (int i = 0; i < 4; ++i)
#pragma unroll
            for (int j = 0; j < 4; ++j) {
                acc[i][j] = __builtin_amdgcn_mfma_f32_16x16x32_bf16(ah[i], bh[j], acc[i][j], 0, 0, 0);
                acc[i][j] = __builtin_amdgcn_mfma_f32_16x16x32_bf16(al[i], bh[j], acc[i][j], 0, 0, 0);
                acc[i][j] = __builtin_amdgcn_mfma_f32_16x16x32_bf16(ah[i], bl[j], acc[i][j], 0, 0, 0);
            }
    }
#pragma unroll
    for (int i = 0; i < 4; ++i) {
        int row0 = rowBase + i * 16 + (lane >> 4) * 4;
#pragma unroll
        for (int j = 0; j < 4; ++j) {
            int col = colBase + j * 16 + lr;
#pragma unroll
            for (int r = 0; r < 4; ++r) {
                int row = row0 + r;
                if (row < M) {
                    float v = acc[i][j][r];
                    if (Cp) {
                        u16 h = f2bf(v); u16 l = f2bf(v - bf2f(h));
                        unsigned int pv = (unsigned int)h | ((unsigned int)l << 16);
                        long idx = xgfmt ? (((long)(row & 1023) * 2048 + col) * 8 + (row >> 10))
                                         : (bz * sC + (long)row * N + col);
                        Cp[idx] = pv;
                    } else if (Ch) {
                        long idx = bz * sC + (long)row * N + col;
                        u16 h = f2bf(v);
                        Ch[idx] = h;
                        Cl[idx] = f2bf(v - bf2f(h));
                    } else {
                        Cf[bz * sC + (long)row * N + col] = v;
                    }
                }
            }
        }
    }
}

// ---------------- fused 2-layer persistent LSTM ----------------
__global__ __launch_bounds__(256, 1)
void k_lstm2(const u16* __restrict__ Wh1, const u16* __restrict__ Wl1,
             const u16* __restrict__ Wh2, const u16* __restrict__ Wl2,
             const u16* __restrict__ Uh2, const u16* __restrict__ Ul2,
             const unsigned int* __restrict__ xg1,
             const float* __restrict__ bias2,
             unsigned int* __restrict__ hw1, unsigned int* __restrict__ hw2,
             unsigned int* __restrict__ fl1, unsigned int* __restrict__ fl2)
{
    __shared__ u16 ldsWh[64 * 512];          // Whh hi shard (64KB)
    __shared__ unsigned int outb[2][128];    // double-buffered outgoing shard (1KB)

    const int bid = blockIdx.x;
    const bool isL2 = bid >= 32;
    const int blk = isL2 ? bid - 32 : bid;
    const int tid = threadIdx.x;
    const int lane = tid & 63;
    const int wave = tid >> 6;
    const int lr = lane & 15;
    const int lkh = lane >> 4;
    const int lk = lkh * 8;
    const int grow = (lr & 3) * 512 + blk * 16 + wave * 4 + (lr >> 2);

    const u16* WhA = isL2 ? Wh2 : Wh1;
    const u16* WlA = isL2 ? Wl2 : Wl1;

    // stage Whh hi into swizzled LDS (proven layout: conflict-free)
    for (int i = tid; i < 64 * 64; i += 256) {
        int rl = i >> 6;
        int col = (i & 63) * 8;
        int g = (rl & 3) * 512 + blk * 16 + (rl >> 4) * 4 + ((rl >> 2) & 3);
        int sw = rl * 512 + (col ^ ((rl & 15) << 3));
        *reinterpret_cast<bf16x8*>(&ldsWh[sw]) =
            *reinterpret_cast<const bf16x8*>(WhA + (long)g * 512 + col);
    }
    __syncthreads();

    const int myrl = wave * 16 + lr;
    const int swz = (myrl & 15) << 3;
    const int basel = lane & ~3;
    const bool writer = ((lane & 3) == 0) && (lkh < 2);
    const int uloc = wave * 4 + (lr >> 2);
    float cc[4] = {0.f, 0.f, 0.f, 0.f};
    const float bv = isL2 ? bias2[grow] : 0.f;
    unsigned int* hwOut = isL2 ? hw2 : hw1;
    unsigned int* flOut = isL2 ? fl2 : fl1;

    // wave0-only: lanes<32 watch pa's flag lines, lanes>=32 watch pb's (or pass). BOUNDED.
    auto waitf = [&](const unsigned int* pa, const unsigned int* pb) {
        const unsigned int* p = (lane < 32) ? (pa + lane * 16)
                                            : (pb ? (pb + (lane - 32) * 16) : nullptr);
        for (int g = 0; g < 131072; ++g) {
            unsigned int f = p ? __hip_atomic_load(p, __ATOMIC_RELAXED, __HIP_MEMORY_SCOPE_AGENT) : 1u;
            if (__ballot(f != 0) == ~0ULL) break;
            __builtin_amdgcn_s_sleep(1);
        }
        asm volatile("" ::: "memory");
    };

    // A-fragment (batch=lr, units s*32+lk..+7) direct from global wire [blk][b8][u16]
    // (round-8-proven freshness & layout)
    auto hfrag = [&](const unsigned int* slot, int s, bf16x8& hi, bf16x8& lo) {
        if (lr < 8) {
            const unsigned int* hp = slot + (s * 2 + (lkh >> 1)) * 128 + lr * 16 + (lkh & 1) * 8;
            u32x4 wa = *reinterpret_cast<const u32x4*>(hp);
            u32x4 wb = *reinterpret_cast<const u32x4*>(hp + 4);
            union { unsigned int d[4]; bf16x8 v; } H, L;
            H.d[0] = __builtin_amdgcn_perm(wa.y, wa.x, 0x05040100u);
            L.d[0] = __builtin_amdgcn_perm(wa.y, wa.x, 0x07060302u);
            H.d[1] = __builtin_amdgcn_perm(wa.w, wa.z, 0x05040100u);
            L.d[1] = __builtin_amdgcn_perm(wa.w, wa.z, 0x07060302u);
            H.d[2] = __builtin_amdgcn_perm(wb.y, wb.x, 0x05040100u);
            L.d[2] = __builtin_amdgcn_perm(wb.y, wb.x, 0x07060302u);
            H.d[3] = __builtin_amdgcn_perm(wb.w, wb.z, 0x05040100u);
            L.d[3] = __builtin_amdgcn_perm(wb.w, wb.z, 0x07060302u);
            hi = H.v; lo = L.v;
        } else {
            hi = (bf16x8){0,0,0,0,0,0,0,0};
            lo = (bf16x8){0,0,0,0,0,0,0,0};
        }
    };

    // xg prefetch pipeline, depth 4 (L1 only)
    auto xgload = [&](int t) {
        u32x4 v = (u32x4){0, 0, 0, 0};
        if (lkh < 2 && t < T_)
            v = *reinterpret_cast<const u32x4*>(xg1 + ((long)t * 2048 + grow) * 8 + lkh * 4);
        return v;
    };
    u32x4 xq0 = (u32x4){0,0,0,0}, xq1 = xq0, xq2 = xq0, xq3 = xq0;
    if (!isL2) { xq0 = xgload(0); xq1 = xgload(1); xq2 = xgload(2); xq3 = xgload(3); }

#pragma unroll 1
    for (int ct = 0; ct < T_; ++ct) {
        if (wave == 0) {
            if (!isL2) waitf(fl1 + (long)ct * 512, nullptr);
            else       waitf(fl2 + (long)ct * 512, fl1 + (long)(ct + 1) * 512);
        }
        __syncthreads();                       // release: producer data visible

        f32x4 acc;
        if (!isL2) {
            const unsigned int* s1 = hw1 + (long)ct * 4096;
            f32x4 a0, a1, a2, a3;
            a0.x = bf2f((u16)(xq0.x & 0xffff)) + bf2f((u16)(xq0.x >> 16));
            a0.y = bf2f((u16)(xq0.y & 0xffff)) + bf2f((u16)(xq0.y >> 16));
            a0.z = bf2f((u16)(xq0.z & 0xffff)) + bf2f((u16)(xq0.z >> 16));
            a0.w = bf2f((u16)(xq0.w & 0xffff)) + bf2f((u16)(xq0.w >> 16));
            a1 = (f32x4){0.f,0.f,0.f,0.f}; a2 = a1; a3 = a1;
            xq0 = xq1; xq1 = xq2; xq2 = xq3; xq3 = xgload(ct + 4);
#pragma unroll
            for (int s = 0; s < 16; s += 2) {
                bf16x8 h0, l0, h1, l1;
                hfrag(s1, s, h0, l0);
                hfrag(s1, s + 1, h1, l1);
                int c0 = (s * 32 + lk) ^ swz;
                int c1 = ((s + 1) * 32 + lk) ^ swz;
                bf16x8 wh0 = *reinterpret_cast<const bf16x8*>(&ldsWh[myrl * 512 + c0]);
                bf16x8 wh1 = *reinterpret_cast<const bf16x8*>(&ldsWh[myrl * 512 + c1]);
                long w0 = (long)grow * 512 + s * 32 + lk;
                bf16x8 wl0 = *reinterpret_cast<const bf16x8*>(WlA + w0);
                bf16x8 wl1 = *reinterpret_cast<const bf16x8*>(WlA + w0 + 32);
                a0 = __builtin_amdgcn_mfma_f32_16x16x32_bf16(h0, wh0, a0, 0, 0, 0);
                a1 = __builtin_amdgcn_mfma_f32_16x16x32_bf16(h1, wh1, a1, 0, 0, 0);
                a2 = __builtin_amdgcn_mfma_f32_16x16x32_bf16(l0, wh0, a2, 0, 0, 0);
                a3 = __builtin_amdgcn_mfma_f32_16x16x32_bf16(l1, wh1, a3, 0, 0, 0);
                a0 = __builtin_amdgcn_mfma_f32_16x16x32_bf16(h0, wl0, a0, 0, 0, 0);
                a1 = __builtin_amdgcn_mfma_f32_16x16x32_bf16(h1, wl1, a1, 0, 0, 0);
            }
            acc = (a0 + a2) + (a1 + a3);
        } else {
            const unsigned int* s2 = hw2 + (long)ct * 4096;
            const unsigned int* s1 = hw1 + (long)(ct + 1) * 4096;
            f32x4 wa0 = (f32x4){bv, bv, bv, bv};
            f32x4 z = (f32x4){0.f,0.f,0.f,0.f};
            f32x4 wa1 = z, wa2 = z, wa3 = z, ua0 = z, ua1 = z, ua2 = z, ua3 = z;
#pragma unroll
            for (int s = 0; s < 16; s += 2) {
                bf16x8 h0, l0, h1, l1, g0, m0, g1, m1;
                hfrag(s2, s, h0, l0);
                hfrag(s2, s + 1, h1, l1);
                hfrag(s1, s, g0, m0);
                hfrag(s1, s + 1, g1, m1);
                int c0 = (s * 32 + lk) ^ swz;
                int c1 = ((s + 1) * 32 + lk) ^ swz;
                bf16x8 wh0 = *reinterpret_cast<const bf16x8*>(&ldsWh[myrl * 512 + c0]);
                bf16x8 wh1 = *reinterpret_cast<const bf16x8*>(&ldsWh[myrl * 512 + c1]);
                long w0 = (long)grow * 512 + s * 32 + lk;
                bf16x8 wl0 = *reinterpret_cast<const bf16x8*>(WlA + w0);
                bf16x8 wl1 = *reinterpret_cast<const bf16x8*>(WlA + w0 + 32);
                bf16x8 uh0 = *reinterpret_cast<const bf16x8*>(Uh2 + w0);
                bf16x8 uh1 = *reinterpret_cast<const bf16x8*>(Uh2 + w0 + 32);
                bf16x8 ul0 = *reinterpret_cast<const bf16x8*>(Ul2 + w0);
                bf16x8 ul1 = *reinterpret_cast<const bf16x8*>(Ul2 + w0 + 32);
                wa0 = __builtin_amdgcn_mfma_f32_16x16x32_bf16(h0, wh0, wa0, 0, 0, 0);
                wa1 = __builtin_amdgcn_mfma_f32_16x16x32_bf16(h1, wh1, wa1, 0, 0, 0);
                ua0 = __builtin_amdgcn_mfma_f32_16x16x32_bf16(g0, uh0, ua0, 0, 0, 0);
                ua1 = __builtin_amdgcn_mfma_f32_16x16x32_bf16(g1, uh1, ua1, 0, 0, 0);
                wa2 = __builtin_amdgcn_mfma_f32_16x16x32_bf16(l0, wh0, wa2, 0, 0, 0);
                wa3 = __builtin_amdgcn_mfma_f32_16x16x32_bf16(l1, wh1, wa3, 0, 0, 0);
                ua2 = __builtin_amdgcn_mfma_f32_16x16x32_bf16(m0, uh0, ua2, 0, 0, 0);
                ua3 = __builtin_amdgcn_mfma_f32_16x16x32_bf16(m1, uh1, ua3, 0, 0, 0);
                wa0 = __builtin_amdgcn_mfma_f32_16x16x32_bf16(h0, wl0, wa0, 0, 0, 0);
                wa1 = __builtin_amdgcn_mfma_f32_16x16x32_bf16(h1, wl1, wa1, 0, 0, 0);
                ua0 = __builtin_amdgcn_mfma_f32_16x16x32_bf16(g0, ul0, ua0, 0, 0, 0);
                ua1 = __builtin_amdgcn_mfma_f32_16x16x32_bf16(g1, ul1, ua1, 0, 0, 0);
            }
            acc = ((wa0 + wa2) + (wa1 + wa3)) + ((ua0 + ua2) + (ua1 + ua3));
        }

        float hval[4];
#pragma unroll
        for (int r = 0; r < 4; ++r) {
            float v = acc[r];
            float iv = __shfl(v, basel + 0, 64);
            float fv = __shfl(v, basel + 1, 64);
            float gv = __shfl(v, basel + 2, 64);
            float ov = __shfl(v, basel + 3, 64);
            float cn = sigm(fv) * cc[r] + sigm(iv) * tanhf_(gv);
            cc[r] = cn;
            hval[r] = sigm(ov) * tanhf_(cn);
        }
        if (writer) {
#pragma unroll
            for (int r = 0; r < 4; ++r) {
                u16 h = f2bf(hval[r]);
                outb[ct & 1][(lkh * 4 + r) * 16 + uloc] =
                    (unsigned int)h | ((unsigned int)f2bf(hval[r] - bf2f(h)) << 16);
            }
        }
        __syncthreads();                       // outb complete
        if (wave == 0) {
            if (lane < 32) {
                u32x4 v = *reinterpret_cast<const u32x4*>(&outb[ct & 1][lane * 4]);
                unsigned long long* hd = (unsigned long long*)
                    (hwOut + (long)(ct + 1) * 4096 + blk * 128 + lane * 4);
                __hip_atomic_store(hd, (unsigned long long)v.x | ((unsigned long long)v.y << 32),
                                   __ATOMIC_RELAXED, __HIP_MEMORY_SCOPE_AGENT);
                __hip_atomic_store(hd + 1, (unsigned long long)v.z | ((unsigned long long)v.w << 32),
                                   __ATOMIC_RELAXED, __HIP_MEMORY_SCOPE_AGENT);
            }
            asm volatile("s_waitcnt vmcnt(0)" ::: "memory");
            if (tid == 0)
                __hip_atomic_store(flOut + (long)(ct + 1) * 512 + blk * 16, 1u,
                                   __ATOMIC_RELAXED, __HIP_MEMORY_SCOPE_AGENT);
        }
        // no trailing barrier: waves 1-3 wait at next step's release-sync for wave0;
        // next step's writers use the other outb buffer (double-buffered).
    }
}

// ---------------- LayerNorm (reads [blk][b][u] h2 ring, writes split planes) --------
__global__ __launch_bounds__(256)
void k_ln(const unsigned int* __restrict__ hw2,
          const float* __restrict__ gamma, const float* __restrict__ beta,
          u16* __restrict__ nh, u16* __restrict__ nl)
{
    __shared__ float sb[8];
    int m = blockIdx.x;
    int b = m >> 10, t = m & 1023;
    const unsigned int* src = hw2 + (long)(t + 1) * 4096;
    int tid = threadIdx.x;
    int u0 = tid, u1 = tid + 256;
    unsigned int w0 = src[(u0 >> 4) * 128 + b * 16 + (u0 & 15)];
    unsigned int w1 = src[(u1 >> 4) * 128 + b * 16 + (u1 & 15)];
    float x0 = bf2f((u16)(w0 & 0xffff)) + bf2f((u16)(w0 >> 16));
    float x1 = bf2f((u16)(w1 & 0xffff)) + bf2f((u16)(w1 >> 16));
    float s = x0 + x1;
#pragma unroll
    for (int off = 32; off; off >>= 1) s += __shfl_down(s, off, 64);
    int wv = tid >> 6, ln = tid & 63;
    if (ln == 0) sb[wv] = s;
    __syncthreads();
    float mu = (sb[0] + sb[1] + sb[2] + sb[3]) * (1.f / 512.f);
    float d0 = x0 - mu, d1 = x1 - mu;
    float ss = d0 * d0 + d1 * d1;
#pragma unroll
    for (int off = 32; off; off >>= 1) ss += __shfl_down(ss, off, 64);
    if (ln == 0) sb[4 + wv] = ss;
    __syncthreads();
    float var = (sb[4] + sb[5] + sb[6] + sb[7]) * (1.f / 512.f);
    float rstd = rsqrtf(var + 1e-5f);
    float y0 = d0 * rstd * gamma[tid] + beta[tid];
    float y1 = d1 * rstd * gamma[tid + 256] + beta[tid + 256];
    long d = (long)m * 512;
    u16 h0 = f2bf(y0); nh[d + tid] = h0; nl[d + tid] = f2bf(y0 - bf2f(h0));
    u16 h1 = f2bf(y1); nh[d + tid + 256] = h1; nl[d + tid + 256] = f2bf(y1 - bf2f(h1));
}

// chunk sums in f32 from split normed, write split
__global__ __launch_bounds__(256)
void k_chunksum(const u16* __restrict__ nh, const u16* __restrict__ nl,
                u16* __restrict__ ch, u16* __restrict__ cl)
{
    int bk = blockIdx.x;
    int tid = threadIdx.x;
    long base = (long)bk * 32 * 512;
    float s0 = 0.f, s1 = 0.f;
#pragma unroll 4
    for (int i = 0; i < 32; ++i) {
        s0 += bf2f(nh[base + (long)i * 512 + tid]) + bf2f(nl[base + (long)i * 512 + tid]);
        s1 += bf2f(nh[base + (long)i * 512 + tid + 256]) + bf2f(nl[base + (long)i * 512 + tid + 256]);
    }
    long d = (long)bk * 512;
    u16 h0 = f2bf(s0); ch[d + tid] = h0; cl[d + tid] = f2bf(s0 - bf2f(h0));
    u16 h1 = f2bf(s1); ch[d + tid + 256] = h1; cl[d + tid + 256] = f2bf(s1 - bf2f(h1));
}

// eof + in_futctx_probs
__global__ __launch_bounds__(256)
void k_eof(const float* __restrict__ dp, const float* __restrict__ noise, float* __restrict__ ifp)
{
    int bk = blockIdx.x;
    int k = bk & 31;
    long base = (long)bk * 1024;
    int tid = threadIdx.x;
#pragma unroll
    for (int i = 0; i < 4; ++i) {
        int t = tid + i * 256;
        float e;
        if (t < (k + 1) * 32) e = 0.f;
        else e = sigm(dp[base + t] * 0.0441941738241592f + noise[base + t]);
        if (t == 0) ifp[base] = 1.f;
        if (t < 1023) ifp[base + t + 1] = 1.f - e;
    }
}

// expected attention, f32. Block = (b, h, kgroup of 8 pivot rows). 256 blocks.
__global__ __launch_bounds__(256)
void k_attn(const float* __restrict__ qf, const float* __restrict__ kvf,
            const float* __restrict__ ifp, u16* __restrict__ ctxh, u16* __restrict__ ctxl)
{
    int bh = blockIdx.x;
    int b = bh >> 5;
    int h = (bh >> 2) & 7;
    int kg = bh & 3;
    __shared__ float qs[8 * 64];
    __shared__ float tile[64 * 65];
    __shared__ float sc[8 * 1024];
    int tid = threadIdx.x;

    for (int i = tid; i < 512; i += 256) {
        int kq = i >> 6, d = i & 63;
        qs[i] = qf[((long)b * 32 + kg * 8 + kq) * 512 + h * 64 + d];
    }
    __syncthreads();
    for (int t0 = 0; t0 < 1024; t0 += 64) {
        for (int i = tid; i < 4096; i += 256) {
            int tt = i >> 6, d = i & 63;
            tile[tt * 65 + d] = kvf[((long)b * 1024 + t0 + tt) * 1024 + h * 64 + d];
        }
        __syncthreads();
#pragma unroll
        for (int pi = 0; pi < 2; ++pi) {
            int p = tid + pi * 256;
            int kq = p >> 6, tt = p & 63;
            float s = 0.f;
#pragma unroll 8
            for (int d = 0; d < 64; ++d) s += qs[kq * 64 + d] * tile[tt * 65 + d];
            sc[kq * 1024 + t0 + tt] = s * 0.125f;
        }
        __syncthreads();
    }
    {
        int w = tid >> 6, lane = tid & 63;
#pragma unroll
        for (int rr = 0; rr < 2; ++rr) {
            int kq = w * 2 + rr;
            float m = -1e30f;
            float vv[16];
#pragma unroll
            for (int i = 0; i < 16; ++i) {
                vv[i] = sc[kq * 1024 + lane + i * 64];
                m = fmaxf(m, vv[i]);
            }
#pragma unroll
            for (int off = 32; off; off >>= 1) m = fmaxf(m, __shfl_xor(m, off, 64));
            long ibase = ((long)b * 32 + kg * 8 + kq) * 1024;
            float sum = 0.f;
            float wv[16];
#pragma unroll
            for (int i = 0; i < 16; ++i) {
                float pv = ifp[ibase + lane + i * 64];
                float e = __expf(vv[i] - m) * pv;
                wv[i] = e; sum += e;
            }
#pragma unroll
            for (int off = 32; off; off >>= 1) sum += __shfl_xor(sum, off, 64);
            float inv = 1.f / sum;
#pragma unroll
            for (int i = 0; i < 16; ++i) sc[kq * 1024 + lane + i * 64] = wv[i] * inv;
        }
    }
    __syncthreads();
    float c0 = 0.f, c1 = 0.f;
    int kq0 = tid >> 6, d0 = tid & 63;
    int kq1 = (tid + 256) >> 6, d1 = tid & 63;
    for (int t0 = 0; t0 < 1024; t0 += 64) {
        __syncthreads();
        for (int i = tid; i < 4096; i += 256) {
            int tt = i >> 6, d = i & 63;
            tile[tt * 65 + d] = kvf[((long)b * 1024 + t0 + tt) * 1024 + 512 + h * 64 + d];
        }
        __syncthreads();
#pragma unroll 8
        for (int tt = 0; tt < 64; ++tt) {
            float a0 = sc[kq0 * 1024 + t0 + tt];
            float a1 = sc[kq1 * 1024 + t0 + tt];
            c0 += a0 * tile[tt * 65 + d0];
            c1 += a1 * tile[tt * 65 + d1];
        }
    }
    long i0 = ((long)b * 32 + kg * 8 + kq0) * 512 + h * 64 + d0;
    long i1 = ((long)b * 32 + kg * 8 + kq1) * 512 + h * 64 + d1;
    u16 h0 = f2bf(c0); ctxh[i0] = h0; ctxl[i0] = f2bf(c0 - bf2f(h0));
    u16 h1v = f2bf(c1); ctxh[i1] = h1v; ctxl[i1] = f2bf(c1 - bf2f(h1v));
}

// ---------------- launch ----------------
extern "C" void kernel_launch(void* const* d_in, const int* in_sizes, int n_in,
                              void* d_out, int out_size, void* d_ws, size_t ws_size,
                              hipStream_t stream)
{
    const float* input = (const float*)d_in[0];
    const float* noise = (const float*)d_in[3];
    const float* Wih  = (const float*)d_in[4];
    const float* Whh  = (const float*)d_in[5];
    const float* bih  = (const float*)d_in[6];
    const float* bhh  = (const float*)d_in[7];
    const float* gam  = (const float*)d_in[8];
    const float* bet  = (const float*)d_in[9];
    const float* Wcp  = (const float*)d_in[10]; const float* bcp  = (const float*)d_in[11];
    const float* Wff  = (const float*)d_in[12]; const float* bff  = (const float*)d_in[13];
    const float* Wq   = (const float*)d_in[14]; const float* bq   = (const float*)d_in[15];
    const float* Wkv  = (const float*)d_in[16]; const float* bkv  = (const float*)d_in[17];
    const float* Wout = (const float*)d_in[18]; const float* bout = (const float*)d_in[19];
    (void)in_sizes; (void)n_in; (void)out_size; (void)ws_size;

    float* out_ctx = (float*)d_out;
    float* out_ifp = (float*)d_out + 8 * 32 * 512;

    char* p = (char*)d_ws;
    auto alloc = [&](size_t bytes) { char* q = p; p += (bytes + 255) & ~(size_t)255; return q; };
    u16* Xh   = (u16*)alloc(8192ULL * 512 * 2);  u16* Xl   = (u16*)alloc(8192ULL * 512 * 2);
    u16* Wihh = (u16*)alloc(2ULL*2048*512*2);    u16* Wihl = (u16*)alloc(2ULL*2048*512*2);
    u16* Whhh = (u16*)alloc(2ULL*2048*512*2);    u16* Whhl = (u16*)alloc(2ULL*2048*512*2);
    u16* Wcph = (u16*)alloc(512ULL*512*2);       u16* Wcpl = (u16*)alloc(512ULL*512*2);
    u16* Wffh = (u16*)alloc(512ULL*512*2);       u16* Wffl = (u16*)alloc(512ULL*512*2);
    u16* Wqh  = (u16*)alloc(512ULL*512*2);       u16* Wql  = (u16*)alloc(512ULL*512*2);
    u16* Wkvh = (u16*)alloc(1024ULL*512*2);      u16* Wkvl = (u16*)alloc(1024ULL*512*2);
    u16* Wouth= (u16*)alloc(512ULL*512*2);       u16* Woutl= (u16*)alloc(512ULL*512*2);
    float* bias12 = (float*)alloc(4096ULL * 4);
    unsigned int* xg1p = (unsigned int*)alloc(8192ULL * 2048 * 4);   // [t][gate][batch]
    unsigned int* hw1  = (unsigned int*)alloc(1025ULL * 4096 * 4);   // [t][blk][b8][u16]
    unsigned int* hw2  = (unsigned int*)alloc(1025ULL * 4096 * 4);
    unsigned int* fl1  = (unsigned int*)alloc(1025ULL * 512 * 4);
    unsigned int* fl2  = (unsigned int*)alloc(1025ULL * 512 * 4);
    u16* nh   = (u16*)alloc(8192ULL*512*2);      u16* nl   = (u16*)alloc(8192ULL*512*2);
    u16* csh  = (u16*)alloc(256ULL*512*2);       u16* csl  = (u16*)alloc(256ULL*512*2);
    u16* pivh = (u16*)alloc(512ULL*512*2);       u16* pivl = (u16*)alloc(512ULL*512*2); // padded rows
    u16* ffh  = (u16*)alloc(8192ULL*512*2);      u16* ffl  = (u16*)alloc(8192ULL*512*2);
    u16* ctxhb= (u16*)alloc(256ULL*512*2);       u16* ctxlb= (u16*)alloc(256ULL*512*2);
    float* qf  = (float*)alloc(256ULL*512*4);
    float* kvf = (float*)alloc(8192ULL*1024*4);
    float* dp  = (float*)alloc(8ULL*32*1024*4);

    // flags: zero all slots, then mark slot 0 (initial h=0) ready
    hipMemsetAsync(fl1, 0, 1025ULL * 512 * 4, stream);
    hipMemsetAsync(fl2, 0, 1025ULL * 512 * 4, stream);
    hipMemsetAsync(fl1, 1, 32 * 64, stream);
    hipMemsetAsync(fl2, 1, 32 * 64, stream);
    hipMemsetAsync(hw1, 0, 4096 * 4, stream);
    hipMemsetAsync(hw2, 0, 4096 * 4, stream);

    k_split<<<4096, 256, 0, stream>>>(input, Xh, Xl, 8192L * 512);
    k_split<<<2048, 256, 0, stream>>>(Wih, Wihh, Wihl, 2L * 2048 * 512);
    k_split<<<2048, 256, 0, stream>>>(Whh, Whhh, Whhl, 2L * 2048 * 512);
    k_split<<<256, 256, 0, stream>>>(Wcp, Wcph, Wcpl, 512L * 512);
    k_split<<<256, 256, 0, stream>>>(Wff, Wffh, Wffl, 512L * 512);
    k_split<<<256, 256, 0, stream>>>(Wq, Wqh, Wql, 512L * 512);
    k_split<<<512, 256, 0, stream>>>(Wkv, Wkvh, Wkvl, 1024L * 512);
    k_split<<<256, 256, 0, stream>>>(Wout, Wouth, Woutl, 512L * 512);
    k_addvec<<<16, 256, 0, stream>>>(bih, bhh, bias12, 4096);

    // layer-1 input gates ([t][gate][batch] packed), then fused 2-layer recurrence
    k_gemm<<<dim3(16, 64, 1), 256, 0, stream>>>(Xh, Xl, Wihh, Wihl, bias12,
                                                nullptr, nullptr, nullptr, xg1p, 1,
                                                8192, 2048, 512, 0, 0, 0);
    k_lstm2<<<64, 256, 0, stream>>>(Whhh, Whhl, Whhh + 2048L*512, Whhl + 2048L*512,
                                    Wihh + 2048L*512, Wihl + 2048L*512,
                                    xg1p, bias12 + 2048, hw1, hw2, fl1, fl2);

    k_ln<<<8192, 256, 0, stream>>>(hw2, gam, bet, nh, nl);
    k_chunksum<<<256, 256, 0, stream>>>(nh, nl, csh, csl);
    k_gemm<<<dim3(4, 2, 1), 256, 0, stream>>>(csh, csl, Wcph, Wcpl, bcp,
                                              nullptr, pivh, pivl, nullptr, 0, 256, 512, 512, 0, 0, 0);
    k_gemm<<<dim3(4, 2, 1), 256, 0, stream>>>(pivh, pivl, Wqh, Wql, bq,
                                              qf, nullptr, nullptr, nullptr, 0, 256, 512, 512, 0, 0, 0);
    k_gemm<<<dim3(4, 64, 1), 256, 0, stream>>>(nh, nl, Wffh, Wffl, bff,
                                               nullptr, ffh, ffl, nullptr, 0, 8192, 512, 512, 0, 0, 0);
    k_gemm<<<dim3(8, 64, 1), 256, 0, stream>>>(ffh, ffl, Wkvh, Wkvl, bkv,
                                               kvf, nullptr, nullptr, nullptr, 0, 8192, 1024, 512, 0, 0, 0);
    k_gemm<<<dim3(8, 1, 8), 256, 0, stream>>>(pivh, pivl, ffh, ffl, nullptr,
                                              dp, nullptr, nullptr, nullptr, 0, 32, 1024, 512,
                                              32L * 512, 1024L * 512, 32L * 1024);
    k_eof<<<256, 256, 0, stream>>>(dp, noise, out_ifp);
    k_attn<<<256, 256, 0, stream>>>(qf, kvf, out_ifp, ctxhb, ctxlb);
    k_gemm<<<dim3(4, 2, 1), 256, 0, stream>>>(ctxhb, ctxlb, Wouth, Woutl, bout,
                                              out_ctx, nullptr, nullptr, nullptr, 0, 256, 512, 512, 0, 0, 0);
}

// Round 13
// 10230.481 us; speedup vs baseline: 1.7062x; 1.7062x over previous
//
#include <hip/hip_runtime.h>

// Aggregator forward: 2-layer LSTM + LN + chunk pivots + expected multi-head attention.
// B=8,T=1024,F=H=FF=512,K=32,CS=32,NH=8,HD=64. Outputs f32: [8,32,512] ++ [8,32,1024].
// Precision: all matmul operands as (hi,lo) bf16 pairs, bf16x3 MFMA (Ah*Bh+Al*Bh+Ah*Bl).
// LSTM: fused 2-layer persistent kernel, 64 blocks (32/layer). Whh-hi in LDS; Whh-lo and
// Wih2 from global (L2-cached). h wire [t][blk][b8][u16] u32(hi|lo<<16): producer
// bounces shard through LDS, wave0 writes 512B contiguous 8B agent stores (full-line
// write-through); consumers cooperatively stage into padded LDS via plain dwordx4
// (round-9 proven: 9.87ms). Wave0-only flag polling, bounded spin.
// Round-13 edit: L2 compute cleaned — loop1 W-only, loop2 U-only (dead MFMAs removed).

typedef unsigned short u16;
typedef __attribute__((ext_vector_type(8))) short bf16x8;
typedef __attribute__((ext_vector_type(4))) float f32x4;
typedef __attribute__((ext_vector_type(4))) unsigned int u32x4;

#define T_    1024
#define HSTR  20   // LDS stage row stride in u32 (16 data + 4 pad)

__device__ __forceinline__ float bf2f(u16 h) {
    union { unsigned int u; float f; } v; v.u = ((unsigned int)h) << 16; return v.f;
}
__device__ __forceinline__ u16 f2bf(float x) {
    union { float f; unsigned int u; } v; v.f = x;
    unsigned int r = (v.u + 0x7FFFu + ((v.u >> 16) & 1u)) >> 16;
    return (u16)r;
}
__device__ __forceinline__ float sigm(float x) { return 1.f / (1.f + __expf(-x)); }
__device__ __forceinline__ float tanhf_(float x) {
    float e = __expf(-2.f * fabsf(x));
    float t = (1.f - e) / (1.f + e);
    return x < 0.f ? -t : t;
}

// ---------------- split f32 -> (hi,lo) bf16 planes ----------------
__global__ __launch_bounds__(256) void k_split(const float* __restrict__ in,
                                               u16* __restrict__ hi, u16* __restrict__ lo, long n) {
    long i = ((long)blockIdx.x * 256 + threadIdx.x) * 4;
    if (i >= n) return;
    union { u16 h[4]; unsigned long long q; } ph, pl;
#pragma unroll
    for (int j = 0; j < 4; ++j) {
        float v = in[i + j];
        u16 h = f2bf(v);
        ph.h[j] = h;
        pl.h[j] = f2bf(v - bf2f(h));
    }
    *reinterpret_cast<unsigned long long*>(hi + i) = ph.q;
    *reinterpret_cast<unsigned long long*>(lo + i) = pl.q;
}

__global__ __launch_bounds__(256) void k_addvec(const float* __restrict__ a, const float* __restrict__ b,
                                                float* __restrict__ o, int n) {
    int i = blockIdx.x * 256 + threadIdx.x;
    if (i < n) o[i] = a[i] + b[i];
}

// ---------------- bf16x3 MFMA GEMM: C[M,N] = A[M,K] @ B[N,K]^T (+bias) ----------------
__global__ __launch_bounds__(256)
void k_gemm(const u16* __restrict__ Ah, const u16* __restrict__ Al,
            const u16* __restrict__ Bh, const u16* __restrict__ Bl,
            const float* __restrict__ bias,
            float* __restrict__ Cf, u16* __restrict__ Ch, u16* __restrict__ Cl,
            unsigned int* __restrict__ Cp, int xgfmt,
            int M, int N, int K, long sA, long sB, long sC)
{
    const int lane = threadIdx.x & 63;
    const int wave = threadIdx.x >> 6;
    const int wr = wave >> 1, wc = wave & 1;
    const long bz = blockIdx.z;
    const u16* Ahb = Ah + bz * sA;
    const u16* Alb = Al + bz * sA;
    const u16* Bhb = Bh + bz * sB;
    const u16* Blb = Bl + bz * sB;
    const int rowBase = blockIdx.y * 128 + wr * 64;
    const int colBase = blockIdx.x * 128 + wc * 64;
    const int lr = lane & 15;
    const int lk = (lane >> 4) * 8;

    f32x4 acc[4][4];
#pragma unroll
    for (int j = 0; j < 4; ++j) {
        float bv = bias ? bias[colBase + j * 16 + lr] : 0.f;
#pragma unroll
        for (int i = 0; i < 4; ++i) acc[i][j] = (f32x4){bv, bv, bv, bv};
    }
    for (int k0 = 0; k0 < K; k0 += 32) {
        bf16x8 ah[4], al[4], bh[4], bl[4];
#pragma unroll
        for (int i = 0; i < 4; ++i) {
            long off = (long)(rowBase + i * 16 + lr) * K + k0 + lk;
            ah[i] = *reinterpret_cast<const bf16x8*>(Ahb + off);
            al[i] = *reinterpret_cast<const bf16x8*>(Alb + off);
        }
#pragma unroll
        for (int j = 0; j < 4; ++j) {
            long off = (long)(colBase + j * 16 + lr) * K + k0 + lk;
            bh[j] = *reinterpret_cast<const bf16x8*>(Bhb + off);
            bl[j] = *reinterpret_cast<const bf16x8*>(Blb + off);
        }
#pragma unroll
        for (int i = 0; i < 4; ++i)
#pragma unroll
            for (int j = 0; j < 4; ++j) {
                acc[i][j] = __builtin_amdgcn_mfma_f32_16x16x32_bf16(ah[i], bh[j], acc[i][j], 0, 0, 0);
                acc[i][j] = __builtin_amdgcn_mfma_f32_16x16x32_bf16(al[i], bh[j], acc[i][j], 0, 0, 0);
                acc[i][j] = __builtin_amdgcn_mfma_f32_16x16x32_bf16(ah[i], bl[j], acc[i][j], 0, 0, 0);
            }
    }
#pragma unroll
    for (int i = 0; i < 4; ++i) {
        int row0 = rowBase + i * 16 + (lane >> 4) * 4;
#pragma unroll
        for (int j = 0; j < 4; ++j) {
            int col = colBase + j * 16 + lr;
#pragma unroll
            for (int r = 0; r < 4; ++r) {
                int row = row0 + r;
                if (row < M) {
                    float v = acc[i][j][r];
                    if (Cp) {
                        u16 h = f2bf(v); u16 l = f2bf(v - bf2f(h));
                        unsigned int pv = (unsigned int)h | ((unsigned int)l << 16);
                        long idx = xgfmt ? (((long)(row & 1023) * 2048 + col) * 8 + (row >> 10))
                                         : (bz * sC + (long)row * N + col);
                        Cp[idx] = pv;
                    } else if (Ch) {
                        long idx = bz * sC + (long)row * N + col;
                        u16 h = f2bf(v);
                        Ch[idx] = h;
                        Cl[idx] = f2bf(v - bf2f(h));
                    } else {
                        Cf[bz * sC + (long)row * N + col] = v;
                    }
                }
            }
        }
    }
}

// ---------------- fused 2-layer persistent LSTM ----------------
__global__ __launch_bounds__(256, 1)
void k_lstm2(const u16* __restrict__ Wh1, const u16* __restrict__ Wl1,
             const u16* __restrict__ Wh2, const u16* __restrict__ Wl2,
             const u16* __restrict__ Uh2, const u16* __restrict__ Ul2,
             const unsigned int* __restrict__ xg1,
             const float* __restrict__ bias2,
             unsigned int* __restrict__ hw1, unsigned int* __restrict__ hw2,
             unsigned int* __restrict__ fl1, unsigned int* __restrict__ fl2)
{
    __shared__ u16 ldsWh[64 * 512];               // Whh hi shard (64KB)
    __shared__ unsigned int hstA[256 * HSTR];     // staged h slot A (20KB, padded rows)
    __shared__ unsigned int hstB[256 * HSTR];     // staged h slot B (L2 only)
    __shared__ unsigned int outb[128];            // outgoing shard bounce (512B)

    const int bid = blockIdx.x;
    const bool isL2 = bid >= 32;
    const int blk = isL2 ? bid - 32 : bid;
    const int tid = threadIdx.x;
    const int lane = tid & 63;
    const int wave = tid >> 6;
    const int lr = lane & 15;
    const int lkh = lane >> 4;
    const int lk = lkh * 8;
    const int grow = (lr & 3) * 512 + blk * 16 + wave * 4 + (lr >> 2);

    const u16* WhA = isL2 ? Wh2 : Wh1;
    const u16* WlA = isL2 ? Wl2 : Wl1;

    // stage Whh hi into swizzled LDS (proven layout: 0 bank conflicts)
    for (int i = tid; i < 64 * 64; i += 256) {
        int rl = i >> 6;
        int col = (i & 63) * 8;
        int g = (rl & 3) * 512 + blk * 16 + (rl >> 4) * 4 + ((rl >> 2) & 3);
        int sw = rl * 512 + (col ^ ((rl & 15) << 3));
        *reinterpret_cast<bf16x8*>(&ldsWh[sw]) =
            *reinterpret_cast<const bf16x8*>(WhA + (long)g * 512 + col);
    }
    __syncthreads();

    const int myrl = wave * 16 + lr;
    const int swz = (myrl & 15) << 3;
    const int basel = lane & ~3;
    const bool writer = ((lane & 3) == 0) && (lkh < 2);
    const int uloc = wave * 4 + (lr >> 2);
    float cc[4] = {0.f, 0.f, 0.f, 0.f};
    const float bv = isL2 ? bias2[grow] : 0.f;
    unsigned int* hwOut = isL2 ? hw2 : hw1;
    unsigned int* flOut = isL2 ? fl2 : fl1;

    // wave0-only: lanes<32 watch pa's flag lines, lanes>=32 watch pb's (or pass). BOUNDED.
    auto waitf = [&](const unsigned int* pa, const unsigned int* pb) {
        const unsigned int* p = (lane < 32) ? (pa + lane * 16)
                                            : (pb ? (pb + (lane - 32) * 16) : nullptr);
        for (int g = 0; g < 131072; ++g) {
            unsigned int f = p ? __hip_atomic_load(p, __ATOMIC_RELAXED, __HIP_MEMORY_SCOPE_AGENT) : 1u;
            if (__ballot(f != 0) == ~0ULL) break;
            __builtin_amdgcn_s_sleep(1);
        }
        asm volatile("" ::: "memory");
    };

    // cooperative stage: thread tid copies wire row tid (16 u32) into padded LDS slot
    auto stage = [&](const unsigned int* src, unsigned int* dst) {
        const unsigned int* s = src + tid * 16;
        u32x4 v0 = *reinterpret_cast<const u32x4*>(s);
        u32x4 v1 = *reinterpret_cast<const u32x4*>(s + 4);
        u32x4 v2 = *reinterpret_cast<const u32x4*>(s + 8);
        u32x4 v3 = *reinterpret_cast<const u32x4*>(s + 12);
        unsigned int* d = dst + tid * HSTR;
        *reinterpret_cast<u32x4*>(d)      = v0;
        *reinterpret_cast<u32x4*>(d + 4)  = v1;
        *reinterpret_cast<u32x4*>(d + 8)  = v2;
        *reinterpret_cast<u32x4*>(d + 12) = v3;
    };

    // A-fragment from padded LDS stage: batch=lr, units s*32+lk..+7
    auto hfrag = [&](const unsigned int* hst, int s, bf16x8& hi, bf16x8& lo) {
        if (lr < 8) {
            const unsigned int* hp = hst + (s * 16 + (lkh >> 1) * 8 + lr) * HSTR + (lkh & 1) * 8;
            u32x4 wa = *reinterpret_cast<const u32x4*>(hp);
            u32x4 wb = *reinterpret_cast<const u32x4*>(hp + 4);
            union { unsigned int d[4]; bf16x8 v; } H, L;
            H.d[0] = __builtin_amdgcn_perm(wa.y, wa.x, 0x05040100u);
            L.d[0] = __builtin_amdgcn_perm(wa.y, wa.x, 0x07060302u);
            H.d[1] = __builtin_amdgcn_perm(wa.w, wa.z, 0x05040100u);
            L.d[1] = __builtin_amdgcn_perm(wa.w, wa.z, 0x07060302u);
            H.d[2] = __builtin_amdgcn_perm(wb.y, wb.x, 0x05040100u);
            L.d[2] = __builtin_amdgcn_perm(wb.y, wb.x, 0x07060302u);
            H.d[3] = __builtin_amdgcn_perm(wb.w, wb.z, 0x05040100u);
            L.d[3] = __builtin_amdgcn_perm(wb.w, wb.z, 0x07060302u);
            hi = H.v; lo = L.v;
        } else {
            hi = (bf16x8){0,0,0,0,0,0,0,0};
            lo = (bf16x8){0,0,0,0,0,0,0,0};
        }
    };

#pragma unroll 1
    for (int ct = 0; ct < T_; ++ct) {
        // prefetch xg (L1 only) before the wait
        u32x4 xw = (u32x4){0, 0, 0, 0};
        if (!isL2 && lkh < 2)
            xw = *reinterpret_cast<const u32x4*>(xg1 + ((long)ct * 2048 + grow) * 8 + lkh * 4);

        if (wave == 0) {
            if (!isL2) waitf(fl1 + (long)ct * 512, nullptr);
            else       waitf(fl2 + (long)ct * 512, fl1 + (long)(ct + 1) * 512);
        }
        __syncthreads();                       // release: producer data visible

        if (!isL2) stage(hw1 + (long)ct * 4096, hstA);
        else {
            stage(hw2 + (long)ct * 4096, hstA);
            stage(hw1 + (long)(ct + 1) * 4096, hstB);
        }
        __syncthreads();                       // stage complete

        f32x4 acc;
        if (!isL2) {
            f32x4 a0, a1 = (f32x4){0.f, 0.f, 0.f, 0.f};
            a0.x = bf2f((u16)(xw.x & 0xffff)) + bf2f((u16)(xw.x >> 16));
            a0.y = bf2f((u16)(xw.y & 0xffff)) + bf2f((u16)(xw.y >> 16));
            a0.z = bf2f((u16)(xw.z & 0xffff)) + bf2f((u16)(xw.z >> 16));
            a0.w = bf2f((u16)(xw.w & 0xffff)) + bf2f((u16)(xw.w >> 16));
#pragma unroll
            for (int s = 0; s < 16; s += 2) {
                bf16x8 h0, l0, h1, l1;
                hfrag(hstA, s, h0, l0);
                hfrag(hstA, s + 1, h1, l1);
                int c0 = (s * 32 + lk) ^ swz;
                int c1 = ((s + 1) * 32 + lk) ^ swz;
                bf16x8 wh0 = *reinterpret_cast<const bf16x8*>(&ldsWh[myrl * 512 + c0]);
                bf16x8 wh1 = *reinterpret_cast<const bf16x8*>(&ldsWh[myrl * 512 + c1]);
                long w0 = (long)grow * 512 + s * 32 + lk;
                bf16x8 wl0 = *reinterpret_cast<const bf16x8*>(WlA + w0);
                bf16x8 wl1 = *reinterpret_cast<const bf16x8*>(WlA + w0 + 32);
                a0 = __builtin_amdgcn_mfma_f32_16x16x32_bf16(h0, wh0, a0, 0, 0, 0);
                a1 = __builtin_amdgcn_mfma_f32_16x16x32_bf16(h1, wh1, a1, 0, 0, 0);
                a0 = __builtin_amdgcn_mfma_f32_16x16x32_bf16(l0, wh0, a0, 0, 0, 0);
                a1 = __builtin_amdgcn_mfma_f32_16x16x32_bf16(l1, wh1, a1, 0, 0, 0);
                a0 = __builtin_amdgcn_mfma_f32_16x16x32_bf16(h0, wl0, a0, 0, 0, 0);
                a1 = __builtin_amdgcn_mfma_f32_16x16x32_bf16(h1, wl1, a1, 0, 0, 0);
            }
            acc = a0 + a1;
        } else {
            // loop 1: W path only (h2 x Whh, bf16x3)
            f32x4 a0 = (f32x4){bv, bv, bv, bv};
            f32x4 z = (f32x4){0.f, 0.f, 0.f, 0.f};
            f32x4 a1 = z, a2 = z, a3 = z;
#pragma unroll
            for (int s = 0; s < 16; s += 2) {
                bf16x8 h0, l0, h1, l1;
                hfrag(hstA, s, h0, l0);
                hfrag(hstA, s + 1, h1, l1);
                int c0 = (s * 32 + lk) ^ swz;
                int c1 = ((s + 1) * 32 + lk) ^ swz;
                bf16x8 wh0 = *reinterpret_cast<const bf16x8*>(&ldsWh[myrl * 512 + c0]);
                bf16x8 wh1 = *reinterpret_cast<const bf16x8*>(&ldsWh[myrl * 512 + c1]);
                long w0 = (long)grow * 512 + s * 32 + lk;
                bf16x8 wl0 = *reinterpret_cast<const bf16x8*>(WlA + w0);
                bf16x8 wl1 = *reinterpret_cast<const bf16x8*>(WlA + w0 + 32);
                a0 = __builtin_amdgcn_mfma_f32_16x16x32_bf16(h0, wh0, a0, 0, 0, 0);
                a1 = __builtin_amdgcn_mfma_f32_16x16x32_bf16(h1, wh1, a1, 0, 0, 0);
                a2 = __builtin_amdgcn_mfma_f32_16x16x32_bf16(l0, wh0, a2, 0, 0, 0);
                a3 = __builtin_amdgcn_mfma_f32_16x16x32_bf16(l1, wh1, a3, 0, 0, 0);
                a0 = __builtin_amdgcn_mfma_f32_16x16x32_bf16(h0, wl0, a0, 0, 0, 0);
                a1 = __builtin_amdgcn_mfma_f32_16x16x32_bf16(h1, wl1, a1, 0, 0, 0);
            }
            // loop 2: U path only (h1 x Wih2, bf16x3)
            f32x4 b0 = z, b1 = z, b2 = z, b3 = z;
#pragma unroll
            for (int s = 0; s < 16; s += 2) {
                bf16x8 g0, m0, g1, m1;
                hfrag(hstB, s, g0, m0);
                hfrag(hstB, s + 1, g1, m1);
                long w0 = (long)grow * 512 + s * 32 + lk;
                bf16x8 uh0 = *reinterpret_cast<const bf16x8*>(Uh2 + w0);
                bf16x8 uh1 = *reinterpret_cast<const bf16x8*>(Uh2 + w0 + 32);
                bf16x8 ul0 = *reinterpret_cast<const bf16x8*>(Ul2 + w0);
                bf16x8 ul1 = *reinterpret_cast<const bf16x8*>(Ul2 + w0 + 32);
                b0 = __builtin_amdgcn_mfma_f32_16x16x32_bf16(g0, uh0, b0, 0, 0, 0);
                b1 = __builtin_amdgcn_mfma_f32_16x16x32_bf16(g1, uh1, b1, 0, 0, 0);
                b2 = __builtin_amdgcn_mfma_f32_16x16x32_bf16(m0, uh0, b2, 0, 0, 0);
                b3 = __builtin_amdgcn_mfma_f32_16x16x32_bf16(m1, uh1, b3, 0, 0, 0);
                b0 = __builtin_amdgcn_mfma_f32_16x16x32_bf16(g0, ul0, b0, 0, 0, 0);
                b1 = __builtin_amdgcn_mfma_f32_16x16x32_bf16(g1, ul1, b1, 0, 0, 0);
            }
            acc = ((a0 + a2) + (a1 + a3)) + ((b0 + b2) + (b1 + b3));
        }

        float hval[4];
#pragma unroll
        for (int r = 0; r < 4; ++r) {
            float v = acc[r];
            float iv = __shfl(v, basel + 0, 64);
            float fv = __shfl(v, basel + 1, 64);
            float gv = __shfl(v, basel + 2, 64);
            float ov = __shfl(v, basel + 3, 64);
            float cn = sigm(fv) * cc[r] + sigm(iv) * tanhf_(gv);
            cc[r] = cn;
            hval[r] = sigm(ov) * tanhf_(cn);
        }
        if (writer) {
#pragma unroll
            for (int r = 0; r < 4; ++r) {
                u16 h = f2bf(hval[r]);
                outb[(lkh * 4 + r) * 16 + uloc] =
                    (unsigned int)h | ((unsigned int)f2bf(hval[r] - bf2f(h)) << 16);
            }
        }
        __syncthreads();                       // outb complete
        if (wave == 0) {
            if (lane < 32) {
                u32x4 v = *reinterpret_cast<const u32x4*>(&outb[lane * 4]);
                unsigned long long* hd = (unsigned long long*)
                    (hwOut + (long)(ct + 1) * 4096 + blk * 128 + lane * 4);
                __hip_atomic_store(hd, (unsigned long long)v.x | ((unsigned long long)v.y << 32),
                                   __ATOMIC_RELAXED, __HIP_MEMORY_SCOPE_AGENT);
                __hip_atomic_store(hd + 1, (unsigned long long)v.z | ((unsigned long long)v.w << 32),
                                   __ATOMIC_RELAXED, __HIP_MEMORY_SCOPE_AGENT);
            }
            asm volatile("s_waitcnt vmcnt(0)" ::: "memory");
            if (tid == 0)
                __hip_atomic_store(flOut + (long)(ct + 1) * 512 + blk * 16, 1u,
                                   __ATOMIC_RELAXED, __HIP_MEMORY_SCOPE_AGENT);
        }
    }
}

// ---------------- LayerNorm (reads [blk][b][u] h2 ring, writes split planes) --------
__global__ __launch_bounds__(256)
void k_ln(const unsigned int* __restrict__ hw2,
          const float* __restrict__ gamma, const float* __restrict__ beta,
          u16* __restrict__ nh, u16* __restrict__ nl)
{
    __shared__ float sb[8];
    int m = blockIdx.x;
    int b = m >> 10, t = m & 1023;
    const unsigned int* src = hw2 + (long)(t + 1) * 4096;
    int tid = threadIdx.x;
    int u0 = tid, u1 = tid + 256;
    unsigned int w0 = src[(u0 >> 4) * 128 + b * 16 + (u0 & 15)];
    unsigned int w1 = src[(u1 >> 4) * 128 + b * 16 + (u1 & 15)];
    float x0 = bf2f((u16)(w0 & 0xffff)) + bf2f((u16)(w0 >> 16));
    float x1 = bf2f((u16)(w1 & 0xffff)) + bf2f((u16)(w1 >> 16));
    float s = x0 + x1;
#pragma unroll
    for (int off = 32; off; off >>= 1) s += __shfl_down(s, off, 64);
    int wv = tid >> 6, ln = tid & 63;
    if (ln == 0) sb[wv] = s;
    __syncthreads();
    float mu = (sb[0] + sb[1] + sb[2] + sb[3]) * (1.f / 512.f);
    float d0 = x0 - mu, d1 = x1 - mu;
    float ss = d0 * d0 + d1 * d1;
#pragma unroll
    for (int off = 32; off; off >>= 1) ss += __shfl_down(ss, off, 64);
    if (ln == 0) sb[4 + wv] = ss;
    __syncthreads();
    float var = (sb[4] + sb[5] + sb[6] + sb[7]) * (1.f / 512.f);
    float rstd = rsqrtf(var + 1e-5f);
    float y0 = d0 * rstd * gamma[tid] + beta[tid];
    float y1 = d1 * rstd * gamma[tid + 256] + beta[tid + 256];
    long d = (long)m * 512;
    u16 h0 = f2bf(y0); nh[d + tid] = h0; nl[d + tid] = f2bf(y0 - bf2f(h0));
    u16 h1 = f2bf(y1); nh[d + tid + 256] = h1; nl[d + tid + 256] = f2bf(y1 - bf2f(h1));
}

// chunk sums in f32 from split normed, write split
__global__ __launch_bounds__(256)
void k_chunksum(const u16* __restrict__ nh, const u16* __restrict__ nl,
                u16* __restrict__ ch, u16* __restrict__ cl)
{
    int bk = blockIdx.x;
    int tid = threadIdx.x;
    long base = (long)bk * 32 * 512;
    float s0 = 0.f, s1 = 0.f;
#pragma unroll 4
    for (int i = 0; i < 32; ++i) {
        s0 += bf2f(nh[base + (long)i * 512 + tid]) + bf2f(nl[base + (long)i * 512 + tid]);
        s1 += bf2f(nh[base + (long)i * 512 + tid + 256]) + bf2f(nl[base + (long)i * 512 + tid + 256]);
    }
    long d = (long)bk * 512;
    u16 h0 = f2bf(s0); ch[d + tid] = h0; cl[d + tid] = f2bf(s0 - bf2f(h0));
    u16 h1 = f2bf(s1); ch[d + tid + 256] = h1; cl[d + tid + 256] = f2bf(s1 - bf2f(h1));
}

// eof + in_futctx_probs
__global__ __launch_bounds__(256)
void k_eof(const float* __restrict__ dp, const float* __restrict__ noise, float* __restrict__ ifp)
{
    int bk = blockIdx.x;
    int k = bk & 31;
    long base = (long)bk * 1024;
    int tid = threadIdx.x;
#pragma unroll
    for (int i = 0; i < 4; ++i) {
        int t = tid + i * 256;
        float e;
        if (t < (k + 1) * 32) e = 0.f;
        else e = sigm(dp[base + t] * 0.0441941738241592f + noise[base + t]);
        if (t == 0) ifp[base] = 1.f;
        if (t < 1023) ifp[base + t + 1] = 1.f - e;
    }
}

// expected attention, f32. Block = (b, h, kgroup of 8 pivot rows). 256 blocks.
__global__ __launch_bounds__(256)
void k_attn(const float* __restrict__ qf, const float* __restrict__ kvf,
            const float* __restrict__ ifp, u16* __restrict__ ctxh, u16* __restrict__ ctxl)
{
    int bh = blockIdx.x;
    int b = bh >> 5;
    int h = (bh >> 2) & 7;
    int kg = bh & 3;
    __shared__ float qs[8 * 64];
    __shared__ float tile[64 * 65];
    __shared__ float sc[8 * 1024];
    int tid = threadIdx.x;

    for (int i = tid; i < 512; i += 256) {
        int kq = i >> 6, d = i & 63;
        qs[i] = qf[((long)b * 32 + kg * 8 + kq) * 512 + h * 64 + d];
    }
    __syncthreads();
    for (int t0 = 0; t0 < 1024; t0 += 64) {
        for (int i = tid; i < 4096; i += 256) {
            int tt = i >> 6, d = i & 63;
            tile[tt * 65 + d] = kvf[((long)b * 1024 + t0 + tt) * 1024 + h * 64 + d];
        }
        __syncthreads();
#pragma unroll
        for (int pi = 0; pi < 2; ++pi) {
            int p = tid + pi * 256;
            int kq = p >> 6, tt = p & 63;
            float s = 0.f;
#pragma unroll 8
            for (int d = 0; d < 64; ++d) s += qs[kq * 64 + d] * tile[tt * 65 + d];
            sc[kq * 1024 + t0 + tt] = s * 0.125f;
        }
        __syncthreads();
    }
    {
        int w = tid >> 6, lane = tid & 63;
#pragma unroll
        for (int rr = 0; rr < 2; ++rr) {
            int kq = w * 2 + rr;
            float m = -1e30f;
            float vv[16];
#pragma unroll
            for (int i = 0; i < 16; ++i) {
                vv[i] = sc[kq * 1024 + lane + i * 64];
                m = fmaxf(m, vv[i]);
            }
#pragma unroll
            for (int off = 32; off; off >>= 1) m = fmaxf(m, __shfl_xor(m, off, 64));
            long ibase = ((long)b * 32 + kg * 8 + kq) * 1024;
            float sum = 0.f;
            float wv[16];
#pragma unroll
            for (int i = 0; i < 16; ++i) {
                float pv = ifp[ibase + lane + i * 64];
                float e = __expf(vv[i] - m) * pv;
                wv[i] = e; sum += e;
            }
#pragma unroll
            for (int off = 32; off; off >>= 1) sum += __shfl_xor(sum, off, 64);
            float inv = 1.f / sum;
#pragma unroll
            for (int i = 0; i < 16; ++i) sc[kq * 1024 + lane + i * 64] = wv[i] * inv;
        }
    }
    __syncthreads();
    float c0 = 0.f, c1 = 0.f;
    int kq0 = tid >> 6, d0 = tid & 63;
    int kq1 = (tid + 256) >> 6, d1 = tid & 63;
    for (int t0 = 0; t0 < 1024; t0 += 64) {
        __syncthreads();
        for (int i = tid; i < 4096; i += 256) {
            int tt = i >> 6, d = i & 63;
            tile[tt * 65 + d] = kvf[((long)b * 1024 + t0 + tt) * 1024 + 512 + h * 64 + d];
        }
        __syncthreads();
#pragma unroll 8
        for (int tt = 0; tt < 64; ++tt) {
            float a0 = sc[kq0 * 1024 + t0 + tt];
            float a1 = sc[kq1 * 1024 + t0 + tt];
            c0 += a0 * tile[tt * 65 + d0];
            c1 += a1 * tile[tt * 65 + d1];
        }
    }
    long i0 = ((long)b * 32 + kg * 8 + kq0) * 512 + h * 64 + d0;
    long i1 = ((long)b * 32 + kg * 8 + kq1) * 512 + h * 64 + d1;
    u16 h0 = f2bf(c0); ctxh[i0] = h0; ctxl[i0] = f2bf(c0 - bf2f(h0));
    u16 h1v = f2bf(c1); ctxh[i1] = h1v; ctxl[i1] = f2bf(c1 - bf2f(h1v));
}

// ---------------- launch ----------------
extern "C" void kernel_launch(void* const* d_in, const int* in_sizes, int n_in,
                              void* d_out, int out_size, void* d_ws, size_t ws_size,
                              hipStream_t stream)
{
    const float* input = (const float*)d_in[0];
    const float* noise = (const float*)d_in[3];
    const float* Wih  = (const float*)d_in[4];
    const float* Whh  = (const float*)d_in[5];
    const float* bih  = (const float*)d_in[6];
    const float* bhh  = (const float*)d_in[7];
    const float* gam  = (const float*)d_in[8];
    const float* bet  = (const float*)d_in[9];
    const float* Wcp  = (const float*)d_in[10]; const float* bcp  = (const float*)d_in[11];
    const float* Wff  = (const float*)d_in[12]; const float* bff  = (const float*)d_in[13];
    const float* Wq   = (const float*)d_in[14]; const float* bq   = (const float*)d_in[15];
    const float* Wkv  = (const float*)d_in[16]; const float* bkv  = (const float*)d_in[17];
    const float* Wout = (const float*)d_in[18]; const float* bout = (const float*)d_in[19];
    (void)in_sizes; (void)n_in; (void)out_size; (void)ws_size;

    float* out_ctx = (float*)d_out;
    float* out_ifp = (float*)d_out + 8 * 32 * 512;

    char* p = (char*)d_ws;
    auto alloc = [&](size_t bytes) { char* q = p; p += (bytes + 255) & ~(size_t)255; return q; };
    u16* Xh   = (u16*)alloc(8192ULL * 512 * 2);  u16* Xl   = (u16*)alloc(8192ULL * 512 * 2);
    u16* Wihh = (u16*)alloc(2ULL*2048*512*2);    u16* Wihl = (u16*)alloc(2ULL*2048*512*2);
    u16* Whhh = (u16*)alloc(2ULL*2048*512*2);    u16* Whhl = (u16*)alloc(2ULL*2048*512*2);
    u16* Wcph = (u16*)alloc(512ULL*512*2);       u16* Wcpl = (u16*)alloc(512ULL*512*2);
    u16* Wffh = (u16*)alloc(512ULL*512*2);       u16* Wffl = (u16*)alloc(512ULL*512*2);
    u16* Wqh  = (u16*)alloc(512ULL*512*2);       u16* Wql  = (u16*)alloc(512ULL*512*2);
    u16* Wkvh = (u16*)alloc(1024ULL*512*2);      u16* Wkvl = (u16*)alloc(1024ULL*512*2);
    u16* Wouth= (u16*)alloc(512ULL*512*2);       u16* Woutl= (u16*)alloc(512ULL*512*2);
    float* bias12 = (float*)alloc(4096ULL * 4);
    unsigned int* xg1p = (unsigned int*)alloc(8192ULL * 2048 * 4);   // [t][gate][batch]
    unsigned int* hw1  = (unsigned int*)alloc(1025ULL * 4096 * 4);   // [t][blk][b8][u16]
    unsigned int* hw2  = (unsigned int*)alloc(1025ULL * 4096 * 4);
    unsigned int* fl1  = (unsigned int*)alloc(1025ULL * 512 * 4);
    unsigned int* fl2  = (unsigned int*)alloc(1025ULL * 512 * 4);
    u16* nh   = (u16*)alloc(8192ULL*512*2);      u16* nl   = (u16*)alloc(8192ULL*512*2);
    u16* csh  = (u16*)alloc(256ULL*512*2);       u16* csl  = (u16*)alloc(256ULL*512*2);
    u16* pivh = (u16*)alloc(512ULL*512*2);       u16* pivl = (u16*)alloc(512ULL*512*2); // padded rows
    u16* ffh  = (u16*)alloc(8192ULL*512*2);      u16* ffl  = (u16*)alloc(8192ULL*512*2);
    u16* ctxhb= (u16*)alloc(256ULL*512*2);       u16* ctxlb= (u16*)alloc(256ULL*512*2);
    float* qf  = (float*)alloc(256ULL*512*4);
    float* kvf = (float*)alloc(8192ULL*1024*4);
    float* dp  = (float*)alloc(8ULL*32*1024*4);

    // flags: zero all slots, then mark slot 0 (initial h=0) ready
    hipMemsetAsync(fl1, 0, 1025ULL * 512 * 4, stream);
    hipMemsetAsync(fl2, 0, 1025ULL * 512 * 4, stream);
    hipMemsetAsync(fl1, 1, 32 * 64, stream);
    hipMemsetAsync(fl2, 1, 32 * 64, stream);
    hipMemsetAsync(hw1, 0, 4096 * 4, stream);
    hipMemsetAsync(hw2, 0, 4096 * 4, stream);

    k_split<<<4096, 256, 0, stream>>>(input, Xh, Xl, 8192L * 512);
    k_split<<<2048, 256, 0, stream>>>(Wih, Wihh, Wihl, 2L * 2048 * 512);
    k_split<<<2048, 256, 0, stream>>>(Whh, Whhh, Whhl, 2L * 2048 * 512);
    k_split<<<256, 256, 0, stream>>>(Wcp, Wcph, Wcpl, 512L * 512);
    k_split<<<256, 256, 0, stream>>>(Wff, Wffh, Wffl, 512L * 512);
    k_split<<<256, 256, 0, stream>>>(Wq, Wqh, Wql, 512L * 512);
    k_split<<<512, 256, 0, stream>>>(Wkv, Wkvh, Wkvl, 1024L * 512);
    k_split<<<256, 256, 0, stream>>>(Wout, Wouth, Woutl, 512L * 512);
    k_addvec<<<16, 256, 0, stream>>>(bih, bhh, bias12, 4096);

    // layer-1 input gates ([t][gate][batch] packed), then fused 2-layer recurrence
    k_gemm<<<dim3(16, 64, 1), 256, 0, stream>>>(Xh, Xl, Wihh, Wihl, bias12,
                                                nullptr, nullptr, nullptr, xg1p, 1,
                                                8192, 2048, 512, 0, 0, 0);
    k_lstm2<<<64, 256, 0, stream>>>(Whhh, Whhl, Whhh + 2048L*512, Whhl + 2048L*512,
                                    Wihh + 2048L*512, Wihl + 2048L*512,
                                    xg1p, bias12 + 2048, hw1, hw2, fl1, fl2);

    k_ln<<<8192, 256, 0, stream>>>(hw2, gam, bet, nh, nl);
    k_chunksum<<<256, 256, 0, stream>>>(nh, nl, csh, csl);
    k_gemm<<<dim3(4, 2, 1), 256, 0, stream>>>(csh, csl, Wcph, Wcpl, bcp,
                                              nullptr, pivh, pivl, nullptr, 0, 256, 512, 512, 0, 0, 0);
    k_gemm<<<dim3(4, 2, 1), 256, 0, stream>>>(pivh, pivl, Wqh, Wql, bq,
                                              qf, nullptr, nullptr, nullptr, 0, 256, 512, 512, 0, 0, 0);
    k_gemm<<<dim3(4, 64, 1), 256, 0, stream>>>(nh, nl, Wffh, Wffl, bff,
                                               nullptr, ffh, ffl, nullptr, 0, 8192, 512, 512, 0, 0, 0);
    k_gemm<<<dim3(8, 64, 1), 256, 0, stream>>>(ffh, ffl, Wkvh, Wkvl, bkv,
                                               kvf, nullptr, nullptr, nullptr, 0, 8192, 1024, 512, 0, 0, 0);
    k_gemm<<<dim3(8, 1, 8), 256, 0, stream>>>(pivh, pivl, ffh, ffl, nullptr,
                                              dp, nullptr, nullptr, nullptr, 0, 32, 1024, 512,
                                              32L * 512, 1024L * 512, 32L * 1024);
    k_eof<<<256, 256, 0, stream>>>(dp, noise, out_ifp);
    k_attn<<<256, 256, 0, stream>>>(qf, kvf, out_ifp, ctxhb, ctxlb);
    k_gemm<<<dim3(4, 2, 1), 256, 0, stream>>>(ctxhb, ctxlb, Wouth, Woutl, bout,
                                              out_ctx, nullptr, nullptr, nullptr, 0, 256, 512, 512, 0, 0, 0);
}